// Round 8
// baseline (65.235 us; speedup 1.0000x reference)
//
#include <hip/hip_runtime.h>

#define NVOX 129600             // 60*36*60
#define NCH  512
#define IMH  120                // 480/4
#define IMW  160                // 640/4
#define NPIX (IMH * IMW)        // 19200
#define LSTR2 162               // float2 row stride (even -> 16B-aligned b128)
#define PLANE2 (IMH * LSTR2)    // 19440 float2 = 155,520 B LDS (1 block/CU)
#define NG4  (NVOX / 4)         // 32400 float4 output groups per channel

typedef float vfloat4 __attribute__((ext_vector_type(4)));
typedef float vfloat2 __attribute__((ext_vector_type(2)));

// row*stride + col of the downsampled pixel, or -1 if outside frustum
__device__ __forceinline__ int project_voxel_s(
    int v, const float* __restrict__ pose, const float* __restrict__ origin,
    const float* __restrict__ camk, int flip, int stride)
{
    int gx = v / 2160;                 // 36*60
    int r  = v - gx * 2160;
    int gy = r / 60;
    int gz = r - gy * 60;
    float wx = gx * 0.08f + 0.04f + origin[0];
    float wy = gz * 0.08f + 0.04f + origin[1];
    float wz = gy * 0.08f + 0.04f + origin[2];
    float cx = pose[0]*wx + pose[1]*wy + pose[2]*wz  + pose[3];
    float cy = pose[4]*wx + pose[5]*wy + pose[6]*wz  + pose[7];
    float cz = pose[8]*wx + pose[9]*wy + pose[10]*wz + pose[11];
    float ix = camk[0]*cx + camk[1]*cy + camk[2]*cz;
    float iy = camk[3]*cx + camk[4]*cy + camk[5]*cz;
    float iz = camk[6]*cx + camk[7]*cy + camk[8]*cz;
    float u  = rintf(ix / iz);         // round half-to-even == jnp.round
    float vv = rintf(iy / iz);
    bool ok = (cz > 0.0f) && (u >= 0.0f) && (u < 640.0f)
                          && (vv >= 0.0f) && (vv < 480.0f);
    if (!ok) return -1;
    float colf = flip ? (639.0f - u) : u;
    return (((int)vv) >> 2) * stride + (((int)colf) >> 2);
}

// ---- pass 0: projection -> lin16[NVOX] (padded float2-idx or 0xFFFF) ----
__global__ __launch_bounds__(256) void proj_kernel(
    unsigned short* __restrict__ lin16,
    const float* __restrict__ pose, const float* __restrict__ origin,
    const float* __restrict__ camk, const int* __restrict__ fliplr)
{
    int v = blockIdx.x * 256 + threadIdx.x;
    if (v < NVOX) {
        int l = project_voxel_s(v, pose, origin, camk, fliplr[0], LSTR2);
        lin16[v] = (l >= 0) ? (unsigned short)l : (unsigned short)0xFFFF;
    }
}

// ---- pass 1: one block per CHANNEL PAIR; interleaved float2 plane in LDS ----
__global__ __launch_bounds__(1024, 1) void chan2_kernel(
    const float* __restrict__ x2d, const unsigned short* __restrict__ lin16,
    float* __restrict__ out)
{
    __shared__ vfloat2 plane[PLANE2];   // 155.5 KB: {chA[p], chB[p]} per pixel
    int b = blockIdx.x;                 // 0..255
    int t = threadIdx.x;
    int c0 = b * 2;

    // stage: coalesced NT float4 reads of both planes, b128 interleaved writes
    const vfloat4* srcA = reinterpret_cast<const vfloat4*>(
        x2d + (size_t)c0 * NPIX);
    const vfloat4* srcB = reinterpret_cast<const vfloat4*>(
        x2d + (size_t)(c0 + 1) * NPIX);
#pragma unroll
    for (int i = 0; i < 5; ++i) {
        int j = i * 1024 + t;           // float4 index within plane (0..4799)
        if (j < NPIX / 4) {
            vfloat4 a  = __builtin_nontemporal_load(&srcA[j]);
            vfloat4 b4 = __builtin_nontemporal_load(&srcB[j]);
            int p   = j * 4;
            int row = p / IMW;
            int col = p - row * IMW;    // float4 stays in-row (160%4==0)
            int idx = row * LSTR2 + col;            // even -> 16B aligned
            vfloat4 w0 = {a.x, b4.x, a.y, b4.y};
            vfloat4 w1 = {a.z, b4.z, a.w, b4.w};
            *reinterpret_cast<vfloat4*>(&plane[idx])     = w0;
            *reinterpret_cast<vfloat4*>(&plane[idx + 2]) = w1;
        }
    }
    __syncthreads();

    // gather: software-pipelined. Batch = 4 groups (16 voxels x 2 channels).
    // lin indices for batch i+1 prefetched before batch i's LDS reads+stores,
    // so the global-load waits never sit between store bursts.
    const uint2* lin2 = reinterpret_cast<const uint2*>(lin16);  // 4 u16 each
    vfloat4* outA = reinterpret_cast<vfloat4*>(out + (size_t)c0 * NVOX);
    vfloat4* outB = reinterpret_cast<vfloat4*>(out + (size_t)(c0 + 1) * NVOX);

    const uint2 SENT = make_uint2(0xFFFFFFFFu, 0xFFFFFFFFu);
    uint2 c0_, c1_, c2_, c3_;
    {
        int g0 = t;
        c0_ = lin2[g0];
        c1_ = lin2[g0 + 1024];
        c2_ = lin2[g0 + 2048];
        c3_ = lin2[g0 + 3072];
    }

#define GATHER_K(K, LV)                                                     \
    {   int g = (base + K) * 1024 + t;                                      \
        if (g < NG4) {                                                      \
            unsigned i0 = LV.x & 0xFFFFu, i1 = LV.x >> 16;                  \
            unsigned i2 = LV.y & 0xFFFFu, i3 = LV.y >> 16;                  \
            bool m0 = i0 != 0xFFFFu, m1 = i1 != 0xFFFFu;                    \
            bool m2 = i2 != 0xFFFFu, m3 = i3 != 0xFFFFu;                    \
            vfloat2 p0 = plane[m0 ? i0 : 0u];                               \
            vfloat2 p1 = plane[m1 ? i1 : 0u];                               \
            vfloat2 p2 = plane[m2 ? i2 : 0u];                               \
            vfloat2 p3 = plane[m3 ? i3 : 0u];                               \
            vfloat4 oA = { m0 ? p0.x : 0.0f, m1 ? p1.x : 0.0f,              \
                           m2 ? p2.x : 0.0f, m3 ? p3.x : 0.0f };            \
            vfloat4 oB = { m0 ? p0.y : 0.0f, m1 ? p1.y : 0.0f,              \
                           m2 ? p2.y : 0.0f, m3 ? p3.y : 0.0f };            \
            __builtin_nontemporal_store(oA, &outA[g]);                      \
            __builtin_nontemporal_store(oB, &outB[g]);                      \
        }                                                                   \
    }

#pragma unroll 1
    for (int base = 0; base < 32; base += 4) {
        uint2 n0 = SENT, n1 = SENT, n2 = SENT, n3 = SENT;
        int nb = base + 4;
        if (nb < 32) {                  // prefetch next batch's indices
            int gb = nb * 1024 + t;
            n0 = lin2[gb];                                  // nb+0 <= 28: valid
            n1 = (gb + 1024 < NG4) ? lin2[gb + 1024] : SENT;
            n2 = (gb + 2048 < NG4) ? lin2[gb + 2048] : SENT;
            n3 = (gb + 3072 < NG4) ? lin2[gb + 3072] : SENT;
        }
        GATHER_K(0, c0_)
        GATHER_K(1, c1_)
        GATHER_K(2, c2_)
        GATHER_K(3, c3_)
        c0_ = n0; c1_ = n1; c2_ = n2; c3_ = n3;
    }
#undef GATHER_K
}

// ---------- fallback if d_ws is too small (ws-free, round-1 style) ----------
__global__ __launch_bounds__(256) void fused_kernel(
    const float* __restrict__ x2d, const float* __restrict__ pose,
    const float* __restrict__ origin, const float* __restrict__ camk,
    const int* __restrict__ fliplr, float* __restrict__ out)
{
    long tid = (long)blockIdx.x * blockDim.x + threadIdx.x;
    int g  = (int)(tid % 32400);
    int cg = (int)(tid / 32400);
    if (cg >= 64) return;
    int v0 = g * 4;
    int linv[4];
#pragma unroll
    for (int i = 0; i < 4; ++i)
        linv[i] = project_voxel_s(v0 + i, pose, origin, camk, fliplr[0], IMW);
    int ch0 = cg * 8;
#pragma unroll
    for (int cc = 0; cc < 8; ++cc) {
        int ch = ch0 + cc;
        const float* s = x2d + (size_t)ch * NPIX;
        float4 o;
        o.x = (linv[0] >= 0) ? s[linv[0]] : 0.0f;
        o.y = (linv[1] >= 0) ? s[linv[1]] : 0.0f;
        o.z = (linv[2] >= 0) ? s[linv[2]] : 0.0f;
        o.w = (linv[3] >= 0) ? s[linv[3]] : 0.0f;
        *reinterpret_cast<float4*>(out + (size_t)ch * NVOX + v0) = o;
    }
}

extern "C" void kernel_launch(void* const* d_in, const int* in_sizes, int n_in,
                              void* d_out, int out_size, void* d_ws, size_t ws_size,
                              hipStream_t stream) {
    const float* x2d    = (const float*)d_in[0];
    const float* pose   = (const float*)d_in[1];
    const float* origin = (const float*)d_in[2];
    const float* camk   = (const float*)d_in[3];
    const int*   flip   = (const int*)d_in[6];
    float*       out    = (float*)d_out;

    const size_t lin_bytes = (size_t)NVOX * sizeof(unsigned short); // 259.2 KB
    if (ws_size >= lin_bytes) {
        unsigned short* lin16 = (unsigned short*)d_ws;
        proj_kernel<<<dim3((NVOX + 255) / 256), dim3(256), 0, stream>>>(
            lin16, pose, origin, camk, flip);
        chan2_kernel<<<dim3(NCH / 2), dim3(1024), 0, stream>>>(
            x2d, lin16, out);
    } else {
        fused_kernel<<<dim3(8100), dim3(256), 0, stream>>>(
            x2d, pose, origin, camk, flip, out);
    }
}